// Round 1
// 448.672 us; speedup vs baseline: 1.0474x; 1.0474x over previous
//
#include <hip/hip_runtime.h>

#define B_    256
#define N_    256
#define DIN   768
#define DOUT  300
#define DOUTP 320           // padded to 20*16
#define M_    (B_*N_)       // 65536
#define HP_ELEMS (M_*DOUT)  // 19660800
#define NEG_INF -9.0e15f

typedef _Float16 f16;
typedef __attribute__((ext_vector_type(8))) _Float16 f16x8;
typedef __attribute__((ext_vector_type(4))) _Float16 f16x4;
typedef __attribute__((ext_vector_type(4))) float    f32x4;

__device__ __forceinline__ void async_copy16(void* lds, const void* g) {
    __builtin_amdgcn_global_load_lds(
        (const __attribute__((address_space(1))) void*)g,
        (__attribute__((address_space(3))) void*)lds, 16, 0, 0);
}

// ---------------- kernel 0: Wt[n][k] = f16(W[k][n]), zero-pad n>=300 -------
__global__ __launch_bounds__(256) void prep_wt(const float* __restrict__ W,
                                               f16* __restrict__ Wt) {
    int idx = blockIdx.x * 256 + threadIdx.x;      // over DOUTP*DIN
    if (idx >= DOUTP * DIN) return;
    int n = idx / DIN, k = idx - n * DIN;
    float v = (n < DOUT) ? W[k * DOUT + n] : 0.0f;
    Wt[idx] = (f16)v;
}

// ---------------- kernel 1: Wh = h@W + pos; f_src/f_dst; WhT fp16 to ws ----
// grid 1024 (64 rows/block), 256 threads.
// 2-ahead software pipeline: B triple-buffered LDS (global_load_lds),
// A 2-ahead in regs, 1-ahead LDS write. Counted vmcnt(7) keeps the newest
// prefetch (5 B-DMA + 2 A-loads) in flight across the barrier.
__global__ __launch_bounds__(256, 2) void gemm1(
    const float* __restrict__ h, const f16* __restrict__ Wt,
    const int* __restrict__ positions,
    const float* __restrict__ a_src, const float* __restrict__ a_dst,
    const float* __restrict__ pos_table,
    f16* __restrict__ WhT, float* __restrict__ f_src, float* __restrict__ f_dst)
{
    __shared__ f16 Al[2][64 * 40];      // A: 64 rows x 32 k, stride 40 f16
    __shared__ f16 Bl[3][DOUTP * 32];   // B: 320 n x 32 k, contiguous (DMA target)
    __shared__ float pfs[64][2], pfd[64][2];

    const int tid  = threadIdx.x;
    const int wave = tid >> 6, lane = tid & 63;
    const int quad = lane >> 4, c = lane & 15;
    const int rh = wave & 1;           // row half (32 rows)
    const int chf = wave >> 1;         // col half (10 tiles)
    const int rowbase = blockIdx.x * 64;

    const int brow = lane >> 2;
    const int bj   = (lane & 3) ^ (brow & 3);   // XOR swizzle on k-chunks
    const int ar = tid >> 2, aj = tid & 3;

    const float* abase = h + (size_t)(rowbase + ar) * DIN + aj * 8;

    f32x4 acc[2][10];
#pragma unroll
    for (int rt = 0; rt < 2; ++rt)
#pragma unroll
        for (int i = 0; i < 10; ++i) acc[rt][i] = (f32x4){0.f, 0.f, 0.f, 0.f};

#define STAGE_B(K, BUF) do {                                                   \
    _Pragma("unroll")                                                          \
    for (int i_ = 0; i_ < 5; ++i_) {                                           \
        int chk_ = wave + 4 * i_;                                              \
        int n_ = chk_ * 16 + brow;                                             \
        async_copy16((char*)Bl[(BUF)] + chk_ * 1024,                           \
                     Wt + (size_t)n_ * DIN + (size_t)(K) * 32 + bj * 8);       \
    } } while (0)

#define LOAD_A(K, V0, V1) do {                                                 \
    const float4* s_ = (const float4*)(abase + (size_t)(K) * 32);              \
    V0 = s_[0]; V1 = s_[1]; } while (0)

#define WRITE_A(BUF, V0, V1)                                                   \
    *(f16x8*)&Al[(BUF)][ar * 40 + aj * 8] =                                    \
        (f16x8){(f16)V0.x, (f16)V0.y, (f16)V0.z, (f16)V0.w,                    \
                (f16)V1.x, (f16)V1.y, (f16)V1.z, (f16)V1.w}

    float4 r0a, r0b, r1a, r1b;

    // ---- prologue: tiles 0 and 1 in flight, A(0) written to LDS ----
    STAGE_B(0, 0); LOAD_A(0, r0a, r0b);
    asm volatile("" ::: "memory");     // order fence: tile-0 ops before tile-1 ops
    STAGE_B(1, 1); LOAD_A(1, r1a, r1b);
    WRITE_A(0, r0a, r0b);
    asm volatile("s_waitcnt vmcnt(7)" ::: "memory");  // tile0 done; tile1 (7 ops) in flight
    asm volatile("s_waitcnt lgkmcnt(0)" ::: "memory");
    __builtin_amdgcn_s_barrier();
    asm volatile("" ::: "memory");

    // iter KT: compute tile KT from Bl[CB]/Al[CA]; prefetch tile KT+2 into
    // Bl[NB] + regs; write A(KT+1) to Al[CA^1]; counted vmcnt + raw barrier.
#define ITER(KT, CB, NB, CA, PF, WA, BAR) do {                                 \
    if (PF) {                                                                  \
        STAGE_B((KT) + 2, NB);                                                 \
        if ((CA) == 0) { LOAD_A((KT) + 2, r0a, r0b); }                         \
        else           { LOAD_A((KT) + 2, r1a, r1b); }                         \
    }                                                                          \
    {                                                                          \
        f16x8 af0 = *(const f16x8*)&Al[(CA)][(rh * 32 + c) * 40 + quad * 8];   \
        f16x8 af1 = *(const f16x8*)&Al[(CA)][(rh * 32 + 16 + c) * 40 + quad * 8]; \
        _Pragma("unroll")                                                      \
        for (int i_ = 0; i_ < 10; ++i_) {                                      \
            int n_ = (chf * 10 + i_) * 16 + c;                                 \
            f16x8 bf = *(const f16x8*)&Bl[(CB)][n_ * 32 + (quad ^ (n_ & 3)) * 8]; \
            acc[0][i_] = __builtin_amdgcn_mfma_f32_16x16x32_f16(af0, bf, acc[0][i_], 0, 0, 0); \
            acc[1][i_] = __builtin_amdgcn_mfma_f32_16x16x32_f16(af1, bf, acc[1][i_], 0, 0, 0); \
        }                                                                      \
    }                                                                          \
    if (WA) {                                                                  \
        if ((CA) == 0) { WRITE_A((CA) ^ 1, r1a, r1b); }                        \
        else           { WRITE_A((CA) ^ 1, r0a, r0b); }                        \
    }                                                                          \
    if (BAR) {                                                                 \
        if (PF) { asm volatile("s_waitcnt vmcnt(7)" ::: "memory"); }           \
        else    { asm volatile("s_waitcnt vmcnt(0)" ::: "memory"); }           \
        asm volatile("s_waitcnt lgkmcnt(0)" ::: "memory");                     \
        __builtin_amdgcn_s_barrier();                                          \
        asm volatile("" ::: "memory");                                         \
    }                                                                          \
} while (0)

    for (int kb = 0; kb < 18; kb += 6) {
        ITER(kb + 0, 0, 2, 0, 1, 1, 1);
        ITER(kb + 1, 1, 0, 1, 1, 1, 1);
        ITER(kb + 2, 2, 1, 0, 1, 1, 1);
        ITER(kb + 3, 0, 2, 1, 1, 1, 1);
        ITER(kb + 4, 1, 0, 0, 1, 1, 1);
        ITER(kb + 5, 2, 1, 1, 1, 1, 1);
    }
    ITER(18, 0, 2, 0, 1, 1, 1);
    ITER(19, 1, 0, 1, 1, 1, 1);
    ITER(20, 2, 1, 0, 1, 1, 1);
    ITER(21, 0, 2, 1, 1, 1, 1);   // prefetches tile 23
    ITER(22, 1, 0, 0, 0, 1, 1);   // no prefetch; drain; write A(23)
    ITER(23, 2, 1, 1, 0, 0, 0);   // last tile, no barrier

#undef ITER
#undef WRITE_A
#undef LOAD_A
#undef STAGE_B

    // ---- epilogue: pos add, f_src/f_dst partials, WhT store ----
    const int bidx  = rowbase >> 8;
    const int mloc  = (rowbase & 255);

    int posr[2][4];
#pragma unroll
    for (int rt = 0; rt < 2; ++rt)
#pragma unroll
        for (int r = 0; r < 4; ++r)
            posr[rt][r] = positions[rowbase + rh * 32 + rt * 16 + quad * 4 + r];

    float fs[2][4] = {{0,0,0,0},{0,0,0,0}}, fd[2][4] = {{0,0,0,0},{0,0,0,0}};
#pragma unroll
    for (int i = 0; i < 10; ++i) {
        int col = (chf * 10 + i) * 16 + c;
        if (col < DOUT) {
            float as = a_src[col], ad = a_dst[col];
#pragma unroll
            for (int rt = 0; rt < 2; ++rt)
#pragma unroll
                for (int r = 0; r < 4; ++r) {
                    float v = acc[rt][i][r] + pos_table[posr[rt][r] * DOUT + col];
                    acc[rt][i][r] = v;
                    fs[rt][r] += v * as;
                    fd[rt][r] += v * ad;
                }
        } else {
#pragma unroll
            for (int rt = 0; rt < 2; ++rt)
#pragma unroll
                for (int r = 0; r < 4; ++r) acc[rt][i][r] = 0.0f;
        }
    }
#pragma unroll
    for (int off = 1; off < 16; off <<= 1) {
#pragma unroll
        for (int rt = 0; rt < 2; ++rt)
#pragma unroll
            for (int r = 0; r < 4; ++r) {
                fs[rt][r] += __shfl_xor(fs[rt][r], off, 16);
                fd[rt][r] += __shfl_xor(fd[rt][r], off, 16);
            }
    }
    if (c == 0) {
#pragma unroll
        for (int rt = 0; rt < 2; ++rt)
#pragma unroll
            for (int r = 0; r < 4; ++r) {
                int row = rh * 32 + rt * 16 + quad * 4 + r;
                pfs[row][chf] = fs[rt][r];
                pfd[row][chf] = fd[rt][r];
            }
    }
    // WhT[b][col][m] fp16
#pragma unroll
    for (int i = 0; i < 10; ++i) {
        int col = (chf * 10 + i) * 16 + c;
#pragma unroll
        for (int rt = 0; rt < 2; ++rt) {
            int mrow = mloc + rh * 32 + rt * 16 + quad * 4;
            f16x4 u = (f16x4){(f16)acc[rt][i][0], (f16)acc[rt][i][1],
                              (f16)acc[rt][i][2], (f16)acc[rt][i][3]};
            *(f16x4*)(WhT + ((size_t)bidx * DOUTP + col) * N_ + mrow) = u;
        }
    }
    __syncthreads();
    if (tid < 64) {
        f_src[rowbase + tid] = pfs[tid][0] + pfs[tid][1];
        f_dst[rowbase + tid] = pfd[tid][0] + pfd[tid][1];
    }
}

// ---------------- kernel 2: fused masked-softmax + h_prime = att @ Wh ------
// grid 1024 (64 rows/block), 256 threads.
// Phase 0: compute softmax for 64 rows, write att (output), keep P in LDS f16.
// Phase 1: GEMM P @ WhT from LDS, B double-buffered 1-ahead.
__global__ __launch_bounds__(256, 2) void fused2(
    const float* __restrict__ adj, const float* __restrict__ f_src,
    const float* __restrict__ f_dst, const f16* __restrict__ WhT,
    float* __restrict__ att, float* __restrict__ hp)
{
    __shared__ f16 Pl[64 * 264];        // P: 64 rows x 256 k, stride 264 f16
    __shared__ f16 Bl[2][DOUTP * 32];

    const int tid  = threadIdx.x;
    const int wave = tid >> 6, lane = tid & 63;
    const int quad = lane >> 4, c = lane & 15;
    const int rh = wave & 1;
    const int chf = wave >> 1;
    const int rowbase = blockIdx.x * 64;
    const int bidx = rowbase >> 8;

    const int brow = lane >> 2;
    const int bj   = (lane & 3) ^ (brow & 3);

#define STAGE_B2(K, BUF) do {                                                  \
    _Pragma("unroll")                                                          \
    for (int i_ = 0; i_ < 5; ++i_) {                                           \
        int chk_ = wave + 4 * i_;                                              \
        int n_ = chk_ * 16 + brow;                                             \
        async_copy16((char*)Bl[(BUF)] + chk_ * 1024,                           \
                     WhT + ((size_t)bidx * DOUTP + n_) * N_ + (size_t)(K) * 32 + bj * 8); \
    } } while (0)

    // B tiles 0,1 in flight under the softmax phase
    STAGE_B2(0, 0);
    STAGE_B2(1, 1);

    // ---- phase 0: masked softmax for 64 rows; att out + P into LDS ----
    {
        float4 fd4 = *(const float4*)(f_dst + bidx * N_ + lane * 4);
        const float* arow = adj + (size_t)(rowbase + wave * 16) * N_ + lane * 4;
        float4 nx = *(const float4*)arow;
        for (int rr = 0; rr < 16; ++rr) {
            float4 a4 = nx;
            if (rr < 15) nx = *(const float4*)(arow + (size_t)(rr + 1) * N_);
            const int lrow = wave * 16 + rr;
            const int row  = rowbase + lrow;
            float fs = f_src[row];

            float v, e0, e1, e2, e3;
            v = fs + fd4.x; v = v >= 0.f ? v : 0.2f * v; e0 = a4.x > 0.f ? v : NEG_INF;
            v = fs + fd4.y; v = v >= 0.f ? v : 0.2f * v; e1 = a4.y > 0.f ? v : NEG_INF;
            v = fs + fd4.z; v = v >= 0.f ? v : 0.2f * v; e2 = a4.z > 0.f ? v : NEG_INF;
            v = fs + fd4.w; v = v >= 0.f ? v : 0.2f * v; e3 = a4.w > 0.f ? v : NEG_INF;

            float mx = fmaxf(fmaxf(e0, e1), fmaxf(e2, e3));
#pragma unroll
            for (int off = 1; off < 64; off <<= 1) mx = fmaxf(mx, __shfl_xor(mx, off, 64));

            float p0 = __expf(e0 - mx), p1 = __expf(e1 - mx);
            float p2 = __expf(e2 - mx), p3 = __expf(e3 - mx);
            float s = p0 + p1 + p2 + p3;
#pragma unroll
            for (int off = 1; off < 64; off <<= 1) s += __shfl_xor(s, off, 64);

            float inv = 1.0f / s;
            *(float4*)(att + (size_t)row * N_ + lane * 4) =
                make_float4(p0 * inv, p1 * inv, p2 * inv, p3 * inv);
            *(f16x4*)&Pl[lrow * 264 + lane * 4] =
                (f16x4){(f16)(p0 * inv), (f16)(p1 * inv), (f16)(p2 * inv), (f16)(p3 * inv)};
        }
    }
    __syncthreads();   // P visible; B tiles 0,1 landed

    // ---- phase 1: GEMM, A = P (LDS-resident), B 1-ahead double-buffer ----
    f32x4 acc[2][10];
#pragma unroll
    for (int rt = 0; rt < 2; ++rt)
#pragma unroll
        for (int i = 0; i < 10; ++i) acc[rt][i] = (f32x4){0.f, 0.f, 0.f, 0.f};

#pragma unroll
    for (int kt = 0; kt < 8; ++kt) {
        f16x8 af0 = *(const f16x8*)&Pl[(rh * 32 + c) * 264 + kt * 32 + quad * 8];
        f16x8 af1 = *(const f16x8*)&Pl[(rh * 32 + 16 + c) * 264 + kt * 32 + quad * 8];
#pragma unroll
        for (int i = 0; i < 10; ++i) {
            int n = (chf * 10 + i) * 16 + c;
            f16x8 bf = *(const f16x8*)&Bl[kt & 1][n * 32 + (quad ^ (n & 3)) * 8];
            acc[0][i] = __builtin_amdgcn_mfma_f32_16x16x32_f16(af0, bf, acc[0][i], 0, 0, 0);
            acc[1][i] = __builtin_amdgcn_mfma_f32_16x16x32_f16(af1, bf, acc[1][i], 0, 0, 0);
        }
        if (kt < 7) {
            __syncthreads();                    // all reads of Bl[kt&1] done; tile kt+1 landed
            if (kt + 2 < 8) STAGE_B2(kt + 2, kt & 1);
        }
    }
#undef STAGE_B2

    // epilogue: hp[row][col], col<300
#pragma unroll
    for (int i = 0; i < 10; ++i) {
        int col = (chf * 10 + i) * 16 + c;
        if (col < DOUT) {
#pragma unroll
            for (int rt = 0; rt < 2; ++rt) {
                int row0 = rowbase + rh * 32 + rt * 16 + quad * 4;
#pragma unroll
                for (int r = 0; r < 4; ++r)
                    hp[(size_t)(row0 + r) * DOUT + col] = acc[rt][i][r];
            }
        }
    }
}

extern "C" void kernel_launch(void* const* d_in, const int* in_sizes, int n_in,
                              void* d_out, int out_size, void* d_ws, size_t ws_size,
                              hipStream_t stream)
{
    const float* h         = (const float*)d_in[0];
    const float* adj       = (const float*)d_in[1];
    const int*   positions = (const int*)d_in[2];
    const float* W         = (const float*)d_in[3];
    const float* a_src     = (const float*)d_in[4];
    const float* a_dst     = (const float*)d_in[5];
    const float* pos_table = (const float*)d_in[6];

    float* hp  = (float*)d_out;            // [65536][300]
    float* att = hp + HP_ELEMS;            // [65536][256]

    f16*   Wt    = (f16*)d_ws;                         // 320*768
    f16*   WhT   = Wt + (size_t)DOUTP * DIN;           // 256*320*256
    float* f_src = (float*)(WhT + (size_t)B_ * DOUTP * N_);
    float* f_dst = f_src + M_;

    hipLaunchKernelGGL(prep_wt, dim3((DOUTP * DIN + 255) / 256), dim3(256), 0, stream, W, Wt);
    hipLaunchKernelGGL(gemm1,   dim3(M_ / 64), dim3(256), 0, stream,
                       h, Wt, positions, a_src, a_dst, pos_table, WhT, f_src, f_dst);
    hipLaunchKernelGGL(fused2,  dim3(M_ / 64), dim3(256), 0, stream,
                       adj, f_src, f_dst, WhT, att, hp);
}